// Round 5
// baseline (569.135 us; speedup 1.0000x reference)
//
#include <hip/hip_runtime.h>
#include <hip/hip_bf16.h>

#define NE 1600000
#define NN 100000
#define H 64
#define ED 16
#define TE 128              // edges per block
#define NTB (NE / TE)       // 12500 edge tiles
#define NB1 391             // ceil(NN/256) scan blocks
#define NNB 1563            // ceil(NN/64) node tiles

#define KS  72    // bf16 K-stride for K=64 packs (W1ab, W2, sH)
#define K3S 136   // bf16 row stride, node GEMM (K=128)
#define MS  66    // fp32 row stride for message buffer

typedef __attribute__((ext_vector_type(8))) short short8;
typedef __attribute__((ext_vector_type(4))) float floatx4;

__device__ __forceinline__ unsigned short f2bf(float f) {
    union { float f; unsigned u; } v; v.f = f;
    unsigned r = v.u + 0x7fff + ((v.u >> 16) & 1);
    return (unsigned short)(r >> 16);
}

__device__ __forceinline__ float bf2f(unsigned short u) {
    union { unsigned u; float f; } v; v.u = ((unsigned)u) << 16;
    return v.f;
}

// fast silu: mul+exp+add+rcp+mul (no IEEE divide)
__device__ __forceinline__ float silu(float x) {
    return x * __builtin_amdgcn_rcpf(1.0f + __expf(-x));
}

// ---- prep: x->bf16, weight packs, histogram (fused) --------------------
__global__ void prep_kernel(const float* __restrict__ x,
                            const float* __restrict__ W1,
                            const float* __restrict__ b1,
                            const float* __restrict__ W2,
                            const float* __restrict__ W3,
                            const int* __restrict__ ei,
                            unsigned short* __restrict__ xb,
                            unsigned short* __restrict__ W1abT,
                            unsigned short* __restrict__ W1cT,
                            unsigned short* __restrict__ W2T,
                            unsigned short* __restrict__ W3T,
                            int* __restrict__ cnt) {
    int tid = blockIdx.x * blockDim.x + threadIdx.x;
    int nt = gridDim.x * blockDim.x;
    const float4* xv = (const float4*)x;
    ushort4* xbv = (ushort4*)xb;
    for (int i = tid; i < NN * H / 4; i += nt) {
        float4 v = xv[i];
        ushort4 o;
        o.x = f2bf(v.x); o.y = f2bf(v.y); o.z = f2bf(v.z); o.w = f2bf(v.w);
        xbv[i] = o;
    }
    for (int i = tid; i < 128 * KS; i += nt) {
        int n = i / KS, k = i % KS;
        W1abT[i] = (k < 64) ? f2bf(W1[(size_t)((n < 64) ? k : 64 + k) * 64 + (n & 63)])
                            : (unsigned short)0;
    }
    for (int i = tid; i < 64 * 32; i += nt) {
        int n = i / 32, k = i % 32;
        unsigned short v = 0;
        if (k < 16) v = f2bf(W1[(size_t)(128 + k) * 64 + n]);
        else if (k == 16) v = f2bf(b1[n]);
        W1cT[i] = v;
    }
    for (int i = tid; i < 64 * KS; i += nt) {
        int n = i / KS, k = i % KS;
        W2T[i] = (k < 64) ? f2bf(W2[k * 64 + n]) : (unsigned short)0;
    }
    for (int i = tid; i < 64 * K3S; i += nt) {
        int n = i / K3S, k = i % K3S;
        W3T[i] = (k < 128) ? f2bf(W3[k * 64 + n]) : (unsigned short)0;
    }
    for (int e = tid; e < NE; e += nt) {
        atomicAdd(&cnt[ei[NE + e]], 1);
    }
}

// ---- counting-sort scan ------------------------------------------------
__global__ void scan_block_kernel(const int* __restrict__ cnt,
                                  int* __restrict__ offs,
                                  int* __restrict__ bsums) {
    __shared__ int tmp[256];
    int b = blockIdx.x, i = threadIdx.x, idx = b * 256 + i;
    int v = (idx < NN) ? cnt[idx] : 0;
    tmp[i] = v;
    __syncthreads();
    #pragma unroll
    for (int off = 1; off < 256; off <<= 1) {
        int t2 = (i >= off) ? tmp[i - off] : 0;
        __syncthreads();
        tmp[i] += t2;
        __syncthreads();
    }
    if (idx < NN) offs[idx] = tmp[i] - v;
    if (i == 255) bsums[b] = tmp[255];
}

__global__ void scan_sums_kernel(int* __restrict__ bsums) {
    __shared__ int tmp[512];
    int i = threadIdx.x;
    int v = (i < NB1) ? bsums[i] : 0;
    tmp[i] = v;
    __syncthreads();
    #pragma unroll
    for (int off = 1; off < 512; off <<= 1) {
        int t2 = (i >= off) ? tmp[i - off] : 0;
        __syncthreads();
        tmp[i] += t2;
        __syncthreads();
    }
    if (i < NB1) bsums[i] = tmp[i] - v;
}

__global__ void scan_add_kernel(int* __restrict__ offs,
                                const int* __restrict__ bsums,
                                int* __restrict__ cursor) {
    int b = blockIdx.x, idx = b * 256 + threadIdx.x;
    if (idx < NN) {
        int o = offs[idx] + bsums[b];
        offs[idx] = o;
        cursor[idx] = o;
    }
}

// eid-only scatter: 4B random writes (sequential within each dst run)
__global__ void scatter_kernel(const int* __restrict__ ei,
                               int* __restrict__ cursor,
                               int* __restrict__ sEl) {
    int e = blockIdx.x * 256 + threadIdx.x;   // grid 6250 x 256 == NE
    int dst = ei[NE + e];
    int pos = atomicAdd(&cursor[dst], 1);
    sEl[pos] = e;
}

// ---- y12: yc[node] = [x@W1a | x@W1b] in bf16 (transposed MFMA) ---------
__global__ __launch_bounds__(256) void y12_kernel(
    const unsigned short* __restrict__ xb,
    const unsigned short* __restrict__ W1abT,
    unsigned short* __restrict__ yc) {
    __shared__ unsigned short sW[128 * KS];   // 18432 B
    int t = threadIdx.x;
    {
        const uint4* wv = (const uint4*)W1abT;
        uint4* sv = (uint4*)sW;
        for (int i = t; i < 128 * KS * 2 / 16; i += 256) sv[i] = wv[i];
    }
    __syncthreads();

    int lane = t & 63, w = t >> 6;
    int m = lane & 15, q = lane >> 4;
    int n0 = blockIdx.x * 64;
    int node = n0 + w * 16 + m;
    int nclamp = (node < NN) ? node : (NN - 1);

    floatx4 acc[8];
    #pragma unroll
    for (int i = 0; i < 8; i++) acc[i] = (floatx4){0.f, 0.f, 0.f, 0.f};
    #pragma unroll
    for (int kt = 0; kt < 2; kt++) {
        short8 bfr = *(const short8*)(xb + (size_t)nclamp * H + kt * 32 + q * 8);
        #pragma unroll
        for (int tt = 0; tt < 8; tt++) {
            short8 afr = *(const short8*)(sW + (tt * 16 + m) * KS + kt * 32 + q * 8);
            acc[tt] = __builtin_amdgcn_mfma_f32_16x16x32_bf16(afr, bfr, acc[tt], 0, 0, 0);
        }
    }
    if (node < NN) {
        #pragma unroll
        for (int tt = 0; tt < 8; tt++) {
            ushort4 o;
            o.x = f2bf(acc[tt][0]); o.y = f2bf(acc[tt][1]);
            o.z = f2bf(acc[tt][2]); o.w = f2bf(acc[tt][3]);
            *(ushort4*)(yc + (size_t)node * 128 + tt * 16 + q * 4) = o;
        }
    }
}

// ---- edge: h = silu(y1[src]+y2[dst]+ea@W1c+b1); m = silu(h@W2+b2); agg --
// 128 edges/block, 8 waves. Transposed MFMA (weights=A, edge data=B):
// lane (m,q) owns edge E=w*16+m, channels tt*16+q*4..+3 (contiguous).
__global__ __launch_bounds__(512, 6) void edge_kernel(
    const unsigned short* __restrict__ yc,
    const float* __restrict__ ea,
    const int* __restrict__ ei,
    const int* __restrict__ sEl,
    const unsigned short* __restrict__ W1cT,
    const unsigned short* __restrict__ W2T,
    const float* __restrict__ b2,
    float* __restrict__ agg) {
    __shared__ unsigned short sH[TE * KS];    // 18432 B
    __shared__ float sM[TE * MS];             // 33792 B
    __shared__ int sSrc[TE], sDst[TE], sEid[TE];  // 1536 B

    int t = threadIdx.x;
    int lane = t & 63, w = t >> 6;            // w 0..7
    int m = lane & 15, q = lane >> 4;
    int E = w * 16 + m;

    // phase 0: waves 0-1 resolve sorted eid -> (src,dst)
    if (t < TE) {
        int e = sEl[blockIdx.x * TE + t];
        sEid[t] = e;
        sSrc[t] = ei[e];
        sDst[t] = ei[NE + e];
    }

    // weight fragments (A-operands), L1/L2-hot
    short8 w1c[4], w2f[2][4];
    #pragma unroll
    for (int tt = 0; tt < 4; tt++)
        w1c[tt] = *(const short8*)(W1cT + (tt * 16 + m) * 32 + q * 8);
    #pragma unroll
    for (int kt = 0; kt < 2; kt++)
        #pragma unroll
        for (int tt = 0; tt < 4; tt++)
            w2f[kt][tt] = *(const short8*)(W2T + (tt * 16 + m) * KS + kt * 32 + q * 8);
    __syncthreads();

    // GEMM1 (K=32): (ea@W1c + b1)^T; ea as B-operand, bias via 1.0 at k=16
    int e = sEid[E];
    short8 bf1 = {0, 0, 0, 0, 0, 0, 0, 0};
    if (q < 2) {
        const float4* p = (const float4*)(ea + (size_t)e * ED + q * 8);
        float4 v0 = p[0], v1 = p[1];
        bf1[0] = (short)f2bf(v0.x); bf1[1] = (short)f2bf(v0.y);
        bf1[2] = (short)f2bf(v0.z); bf1[3] = (short)f2bf(v0.w);
        bf1[4] = (short)f2bf(v1.x); bf1[5] = (short)f2bf(v1.y);
        bf1[6] = (short)f2bf(v1.z); bf1[7] = (short)f2bf(v1.w);
    } else if (q == 2) {
        bf1[0] = (short)0x3F80;
    }
    floatx4 acc[4];
    #pragma unroll
    for (int i = 0; i < 4; i++) acc[i] = (floatx4){0.f, 0.f, 0.f, 0.f};
    #pragma unroll
    for (int tt = 0; tt < 4; tt++)
        acc[tt] = __builtin_amdgcn_mfma_f32_16x16x32_bf16(w1c[tt], bf1, acc[tt], 0, 0, 0);

    // epi1: ysum loaded per-lane straight from global (no LDS staging)
    {
        int s = sSrc[E], d = sDst[E];
        const unsigned short* ysp = yc + (size_t)s * 128;
        const unsigned short* ydp = yc + (size_t)d * 128 + 64;
        #pragma unroll
        for (int tt = 0; tt < 4; tt++) {
            int ch = tt * 16 + q * 4;
            ushort4 a4 = *(const ushort4*)(ysp + ch);
            ushort4 d4 = *(const ushort4*)(ydp + ch);
            ushort4 hp;
            hp.x = f2bf(silu(acc[tt][0] + bf2f(a4.x) + bf2f(d4.x)));
            hp.y = f2bf(silu(acc[tt][1] + bf2f(a4.y) + bf2f(d4.y)));
            hp.z = f2bf(silu(acc[tt][2] + bf2f(a4.z) + bf2f(d4.z)));
            hp.w = f2bf(silu(acc[tt][3] + bf2f(a4.w) + bf2f(d4.w)));
            *(ushort4*)(sH + E * KS + ch) = hp;
        }
    }
    __syncthreads();

    // GEMM2: (h@W2)^T; h fragment as B-operand
    floatx4 acc2[4];
    #pragma unroll
    for (int i = 0; i < 4; i++) acc2[i] = (floatx4){0.f, 0.f, 0.f, 0.f};
    #pragma unroll
    for (int kt = 0; kt < 2; kt++) {
        short8 hfr = *(const short8*)(sH + E * KS + kt * 32 + q * 8);
        #pragma unroll
        for (int tt = 0; tt < 4; tt++)
            acc2[tt] = __builtin_amdgcn_mfma_f32_16x16x32_bf16(w2f[kt][tt], hfr, acc2[tt], 0, 0, 0);
    }

    // epi2: messages -> sM (fp32, float2 stores; stride 66 keeps 8B align)
    #pragma unroll
    for (int tt = 0; tt < 4; tt++) {
        int ch = tt * 16 + q * 4;
        float4 bb = *(const float4*)(b2 + ch);
        float2 m0, m1;
        m0.x = silu(acc2[tt][0] + bb.x);
        m0.y = silu(acc2[tt][1] + bb.y);
        m1.x = silu(acc2[tt][2] + bb.z);
        m1.y = silu(acc2[tt][3] + bb.w);
        *(float2*)(sM + E * MS + ch) = m0;
        *(float2*)(sM + E * MS + ch + 2) = m1;
    }
    __syncthreads();

    // segment-reduce: wave w reduces rows [w*16, w*16+16), lane = column
    {
        int c = lane;
        float s = 0.f;
        int cur = sDst[w * 16];
        #pragma unroll
        for (int r = 0; r < 16; r++) {
            int rr = w * 16 + r;
            int d = sDst[rr];
            if (d != cur) {
                atomicAdd(&agg[(size_t)cur * H + c], s);
                s = 0.f;
                cur = d;
            }
            s += sM[rr * MS + c];
        }
        atomicAdd(&agg[(size_t)cur * H + c], s);
    }
}

// ---- node MLP (transposed MFMA) ----------------------------------------
__global__ __launch_bounds__(256) void node_kernel(
    const unsigned short* __restrict__ xb,
    const float* __restrict__ agg,
    const unsigned short* __restrict__ W3T,
    const float* __restrict__ b3,
    float* __restrict__ out) {
    __shared__ unsigned short sW3[64 * K3S];
    __shared__ unsigned short sA[64 * K3S];

    int t = threadIdx.x;
    int n0 = blockIdx.x * 64;

    {
        const uint4* wv = (const uint4*)W3T;
        uint4* sv = (uint4*)sW3;
        for (int i = t; i < 64 * K3S * 2 / 16; i += 256) sv[i] = wv[i];
    }
    {
        int nL = t >> 2, sub = t & 3;
        int node = n0 + nL;
        uint4* arow = (uint4*)(sA + nL * K3S);
        if (node < NN) {
            const uint4* xs = (const uint4*)(xb + (size_t)node * H);
            arow[sub * 2]     = xs[sub * 2];
            arow[sub * 2 + 1] = xs[sub * 2 + 1];
            const float4* av = (const float4*)(agg + (size_t)node * H);
            unsigned short tmp[16];
            #pragma unroll
            for (int j = 0; j < 4; j++) {
                float4 v = av[sub * 4 + j];
                tmp[j * 4 + 0] = f2bf(v.x); tmp[j * 4 + 1] = f2bf(v.y);
                tmp[j * 4 + 2] = f2bf(v.z); tmp[j * 4 + 3] = f2bf(v.w);
            }
            uint4* drow = (uint4*)(sA + nL * K3S + 64 + sub * 16);
            drow[0] = ((const uint4*)tmp)[0];
            drow[1] = ((const uint4*)tmp)[1];
        } else {
            uint4 z = {0, 0, 0, 0};
            arow[sub * 2] = z; arow[sub * 2 + 1] = z;
            uint4* drow = (uint4*)(sA + nL * K3S + 64 + sub * 16);
            drow[0] = z; drow[1] = z;
        }
    }
    __syncthreads();

    int w = t >> 6, lane = t & 63;
    int m = lane & 15, q = lane >> 4;
    int node = n0 + w * 16 + m;

    floatx4 acc[4];
    #pragma unroll
    for (int i = 0; i < 4; i++) acc[i] = (floatx4){0.f, 0.f, 0.f, 0.f};
    #pragma unroll
    for (int kt = 0; kt < 4; kt++) {
        short8 bfr = *(const short8*)(sA + (w * 16 + m) * K3S + kt * 32 + q * 8);
        #pragma unroll
        for (int tt = 0; tt < 4; tt++) {
            short8 afr = *(const short8*)(sW3 + (tt * 16 + m) * K3S + kt * 32 + q * 8);
            acc[tt] = __builtin_amdgcn_mfma_f32_16x16x32_bf16(afr, bfr, acc[tt], 0, 0, 0);
        }
    }
    if (node < NN) {
        #pragma unroll
        for (int tt = 0; tt < 4; tt++) {
            float4 bb = *(const float4*)(b3 + tt * 16 + q * 4);
            float4 ov;
            ov.x = silu(acc[tt][0] + bb.x);
            ov.y = silu(acc[tt][1] + bb.y);
            ov.z = silu(acc[tt][2] + bb.z);
            ov.w = silu(acc[tt][3] + bb.w);
            *(float4*)(out + (size_t)node * H + tt * 16 + q * 4) = ov;
        }
    }
}

static inline size_t align256(size_t x) { return (x + 255) & ~(size_t)255; }

extern "C" void kernel_launch(void* const* d_in, const int* in_sizes, int n_in,
                              void* d_out, int out_size, void* d_ws, size_t ws_size,
                              hipStream_t stream) {
    const float* x  = (const float*)d_in[0];
    const int*   ei = (const int*)d_in[1];
    const float* ea = (const float*)d_in[2];
    const float* W1 = (const float*)d_in[3];
    const float* b1 = (const float*)d_in[4];
    const float* W2 = (const float*)d_in[5];
    const float* b2 = (const float*)d_in[6];
    const float* W3 = (const float*)d_in[7];
    const float* b3 = (const float*)d_in[8];
    float* out = (float*)d_out;

    char* ws = (char*)d_ws;
    size_t o = 0;
    float* agg = (float*)(ws + o);                     o = align256(o + (size_t)NN * H * 4);
    unsigned short* xb = (unsigned short*)(ws + o);    o = align256(o + (size_t)NN * H * 2);
    unsigned short* yc = (unsigned short*)(ws + o);    o = align256(o + (size_t)NN * 128 * 2);
    unsigned short* W1abT = (unsigned short*)(ws + o); o = align256(o + 128 * KS * 2);
    unsigned short* W1cT = (unsigned short*)(ws + o);  o = align256(o + 64 * 32 * 2);
    unsigned short* W2T = (unsigned short*)(ws + o);   o = align256(o + 64 * KS * 2);
    unsigned short* W3T = (unsigned short*)(ws + o);   o = align256(o + 64 * K3S * 2);
    int* offs = (int*)(ws + o);                        o = align256(o + (size_t)NN * 4);
    int* bsums = (int*)(ws + o);                       o = align256(o + NB1 * 4);
    int* cnt = (int*)(ws + o);                         o = align256(o + (size_t)NN * 4);
    int* sEl = (int*)(ws + o);                         o = align256(o + (size_t)NE * 4);

    int* cursor = cnt;

    hipMemsetAsync(agg, 0, (size_t)NN * H * sizeof(float), stream);
    hipMemsetAsync(cnt, 0, (size_t)NN * sizeof(int), stream);
    prep_kernel<<<2048, 256, 0, stream>>>(x, W1, b1, W2, W3, ei, xb, W1abT, W1cT, W2T, W3T, cnt);
    scan_block_kernel<<<NB1, 256, 0, stream>>>(cnt, offs, bsums);
    scan_sums_kernel<<<1, 512, 0, stream>>>(bsums);
    scan_add_kernel<<<NB1, 256, 0, stream>>>(offs, bsums, cursor);
    scatter_kernel<<<NE / 256, 256, 0, stream>>>(ei, cursor, sEl);
    y12_kernel<<<NNB, 256, 0, stream>>>(xb, W1abT, yc);
    edge_kernel<<<NTB, 512, 0, stream>>>(yc, ea, ei, sEl, W1cT, W2T, b2, agg);
    node_kernel<<<NNB, 256, 0, stream>>>(xb, agg, W3T, b3, out);
}